// Round 1
// baseline (1130.837 us; speedup 1.0000x reference)
//
#include <hip/hip_runtime.h>
#include <math.h>

// ---------------------------------------------------------------------------
// CausalHFPLayer: B=4, N=4096, D=1024, C=64 -> nc=64 chunks/batch, BC=256
// rfft bins M=33, k_low=4, high bins 29. NH=16, NKV=4, HD=64, T=256.
// All fp32 (round-1 correctness baseline).
// ---------------------------------------------------------------------------

#define AM_CONT 0
#define AM_XLOW 1
#define EP_NONE 0
#define EP_SIGMOID 1
#define EP_FUSELOW 2
#define EP_HIGH 3

// ============================ DFT (rfft) kernel ============================
// thread = (bc, d). Loads 64 time samples, produces 33 complex bins into Xh:
// Xh[bc, f, d] = real bin f (rows 0..32), Xh[bc, 33+f, d] = imag (rows 33..65)
__global__ __launch_bounds__(256) void dft_kernel(const float* __restrict__ X,
                                                  float* __restrict__ Xh) {
  const int d = blockIdx.x * 256 + threadIdx.x;
  const long bc = blockIdx.y;
  const float* xp = X + (bc * 64) * 1024 + d;
  float x[64];
#pragma unroll
  for (int t = 0; t < 64; t++) x[t] = xp[(long)t * 1024];
  // parity split: u[t]=x[t]+x[t+32] (even f), w[t]=x[t]-x[t+32] (odd f)
#pragma unroll
  for (int t = 0; t < 32; t++) {
    float a = x[t], b = x[t + 32];
    x[t] = a + b;
    x[t + 32] = a - b;
  }
  float* outp = Xh + bc * 66 * 1024 + d;
  const float W = -6.283185307179586f / 64.f;
  for (int f = 0; f <= 32; f += 2) {  // even bins use u = x[0..31]
    float sd, cd;
    __sincosf(W * f, &sd, &cd);
    float c = 1.f, s = 0.f, ar = 0.f, ai = 0.f;
#pragma unroll
    for (int t = 0; t < 32; t++) {
      ar = fmaf(x[t], c, ar);
      ai = fmaf(x[t], s, ai);
      float cn = c * cd - s * sd;
      s = s * cd + c * sd;
      c = cn;
    }
    outp[(long)f * 1024] = ar;
    outp[(long)(33 + f) * 1024] = ai;
  }
  for (int f = 1; f <= 31; f += 2) {  // odd bins use w = x[32..63]
    float sd, cd;
    __sincosf(W * f, &sd, &cd);
    float c = 1.f, s = 0.f, ar = 0.f, ai = 0.f;
#pragma unroll
    for (int t = 0; t < 32; t++) {
      ar = fmaf(x[32 + t], c, ar);
      ai = fmaf(x[32 + t], s, ai);
      float cn = c * cd - s * sd;
      s = s * cd + c * sd;
      c = cn;
    }
    outp[(long)f * 1024] = ar;
    outp[(long)(33 + f) * 1024] = ai;
  }
}

// ============================ weight concat ================================
__global__ __launch_bounds__(256) void concat_w(const float* __restrict__ qw,
                                                const float* __restrict__ kw,
                                                const float* __restrict__ vw,
                                                float* __restrict__ W) {
  int i = blockIdx.x * 256 + threadIdx.x;  // float4 index, total 393216
  float4* W4 = (float4*)W;
  if (i < 262144) W4[i] = ((const float4*)qw)[i];
  else if (i < 327680) W4[i] = ((const float4*)kw)[i - 262144];
  else W4[i] = ((const float4*)vw)[i - 327680];
}

// ============================ generic GEMM =================================
// C[M,N] = A[M,K] @ B[N,K]^T with row gather + fused epilogues.
template <int BM, int BN, int AMODE, int EMODE>
__global__ __launch_bounds__(256) void mm_kernel(
    const float* __restrict__ A0, const float* __restrict__ A1, int lda,
    const float* __restrict__ B0, const float* __restrict__ B1, int N, int K,
    float* __restrict__ C0, float* __restrict__ C1,
    const float* __restrict__ Xh, float* __restrict__ XhMut,
    const float* __restrict__ gate, const float* __restrict__ alpha_ptr) {
  constexpr int MI = BM / 16, NI = BN / 16;
  const int z = blockIdx.z;
  const float* A = z ? A1 : A0;
  const float* B = z ? B1 : B0;
  float* C = z ? C1 : C0;
  const int imoff = z ? 33 * 1024 : 0;
  __shared__ float As[16][BM + 4];
  __shared__ float Bs[16][BN + 4];
  const int tid = threadIdx.x;
  const int ty = tid >> 4, tx = tid & 15;
  const int m0 = blockIdx.x * BM, n0 = blockIdx.y * BN;

  long aoff[BM / 64];
#pragma unroll
  for (int it = 0; it < BM / 64; it++) {
    int idx = tid + it * 256;
    int mm = idx >> 2;
    int r = m0 + mm;
    if (AMODE == AM_CONT) {
      aoff[it] = (long)r * lda;
    } else {  // AM_XLOW: r = b*256 + t, t = chunk*4 + f
      int b = r >> 8, t = r & 255;
      aoff[it] = ((long)((b << 6) + (t >> 2)) * 66 + (t & 3)) * 1024 + imoff;
    }
  }
  long boff[BN / 64];
#pragma unroll
  for (int it = 0; it < BN / 64; it++) {
    int idx = tid + it * 256;
    boff[it] = (long)(n0 + (idx >> 2)) * K;
  }

  float acc[MI][NI];
#pragma unroll
  for (int i = 0; i < MI; i++)
#pragma unroll
    for (int j = 0; j < NI; j++) acc[i][j] = 0.f;

  for (int kb = 0; kb < K; kb += 16) {
#pragma unroll
    for (int it = 0; it < BM / 64; it++) {
      int idx = tid + it * 256;
      int mm = idx >> 2, kq = (idx & 3) << 2;
      float4 v = *(const float4*)(A + aoff[it] + kb + kq);
      As[kq + 0][mm] = v.x;
      As[kq + 1][mm] = v.y;
      As[kq + 2][mm] = v.z;
      As[kq + 3][mm] = v.w;
    }
#pragma unroll
    for (int it = 0; it < BN / 64; it++) {
      int idx = tid + it * 256;
      int nn = idx >> 2, kq = (idx & 3) << 2;
      float4 v = *(const float4*)(B + boff[it] + kb + kq);
      Bs[kq + 0][nn] = v.x;
      Bs[kq + 1][nn] = v.y;
      Bs[kq + 2][nn] = v.z;
      Bs[kq + 3][nn] = v.w;
    }
    __syncthreads();
#pragma unroll
    for (int kk = 0; kk < 16; kk++) {
      float a[MI], b[NI];
#pragma unroll
      for (int i = 0; i < MI; i++) a[i] = As[kk][ty * MI + i];
#pragma unroll
      for (int j = 0; j < NI; j++) b[j] = Bs[kk][tx * NI + j];
#pragma unroll
      for (int i = 0; i < MI; i++)
#pragma unroll
        for (int j = 0; j < NI; j++) acc[i][j] = fmaf(a[i], b[j], acc[i][j]);
    }
    __syncthreads();
  }

  float alpha = 0.f;
  if (EMODE == EP_FUSELOW) alpha = 1.f / (1.f + __expf(-alpha_ptr[0]));
#pragma unroll
  for (int i = 0; i < MI; i++) {
    int r = m0 + ty * MI + i;
#pragma unroll
    for (int j = 0; j < NI; j++) {
      int col = n0 + tx * NI + j;
      float v = acc[i][j];
      if (EMODE == EP_NONE) {
        C[(long)r * N + col] = v;
      } else if (EMODE == EP_SIGMOID) {
        C[(long)r * N + col] = 1.f / (1.f + __expf(-v * (1.f / 64.f)));
      } else if (EMODE == EP_FUSELOW) {
        int b = r >> 8, t = r & 255;
        long x = ((long)((b << 6) + (t >> 2)) * 66 + (t & 3)) * 1024 + imoff + col;
        C[(long)r * N + col] = alpha * v + (1.f - alpha) * Xh[x];
      } else {  // EP_HIGH: r = bc*29 + l; in-place A_high = v*g + X_high
        int bc = r / 29, l = r - bc * 29;
        long x = ((long)bc * 66 + 4 + l) * 1024 + imoff + col;
        XhMut[x] = fmaf(v, gate[(long)bc * 1024 + col], Xh[x]);
      }
    }
  }
}

// ============================ attention ====================================
// grid (NH, B, 2). block 256 = one q row per thread. QKV layout (b,t,1536):
// cols 0..1023 Q, 1024..1279 K, 1280..1535 V. Online softmax, K/V via LDS.
__global__ __launch_bounds__(256) void attn_kernel(const float* __restrict__ QKVr,
                                                   const float* __restrict__ QKVi,
                                                   float* __restrict__ Or_,
                                                   float* __restrict__ Oi_) {
  const int h = blockIdx.x, b = blockIdx.y;
  const float* QKV = blockIdx.z ? QKVi : QKVr;
  float* O = blockIdx.z ? Oi_ : Or_;
  const int kvh = h >> 2;
  const int tid = threadIdx.x;  // q row
  __shared__ float Ks[64 * 64];
  __shared__ float Vs[64 * 64];

  float q[64];
  const float* qp = QKV + ((long)(b * 256 + tid)) * 1536 + h * 64;
#pragma unroll
  for (int j = 0; j < 64; j += 4) {
    float4 v = *(const float4*)(qp + j);
    q[j] = v.x; q[j + 1] = v.y; q[j + 2] = v.z; q[j + 3] = v.w;
  }
  float acc[64];
#pragma unroll
  for (int j = 0; j < 64; j++) acc[j] = 0.f;
  float m = -1e30f, l = 0.f;
  const int kend = ((tid >> 2) + 1) << 2;  // (chunk+1)*4

  for (int tile = 0; tile < 4; tile++) {
#pragma unroll
    for (int it = 0; it < 4; it++) {
      int idx = tid + it * 256;       // 0..1023
      int tr = idx >> 4;              // 0..63
      int j4 = (idx & 15) << 2;
      const float* base = QKV + ((long)(b * 256 + tile * 64 + tr)) * 1536 + kvh * 64;
      *(float4*)&Ks[tr * 64 + j4] = *(const float4*)(base + 1024 + j4);
      *(float4*)&Vs[tr * 64 + j4] = *(const float4*)(base + 1280 + j4);
    }
    __syncthreads();
    int cnt = kend - tile * 64;
    cnt = cnt > 64 ? 64 : cnt;
    for (int kp = 0; kp < cnt; kp++) {
      const float* kr = &Ks[kp * 64];
      float s = 0.f;
#pragma unroll
      for (int j = 0; j < 64; j++) s = fmaf(q[j], kr[j], s);
      s *= 0.125f;
      float mn = fmaxf(m, s);
      float sc = __expf(m - mn);
      float p = __expf(s - mn);
      l = l * sc + p;
      m = mn;
      const float* vr = &Vs[kp * 64];
#pragma unroll
      for (int j = 0; j < 64; j++) acc[j] = fmaf(acc[j], sc, p * vr[j]);
    }
    __syncthreads();
  }
  float inv = 1.f / l;
  float* op = O + ((long)(b * 256 + tid)) * 1024 + h * 64;
#pragma unroll
  for (int j = 0; j < 64; j += 4) {
    float4 v;
    v.x = acc[j] * inv; v.y = acc[j + 1] * inv;
    v.z = acc[j + 2] * inv; v.w = acc[j + 3] * inv;
    *(float4*)(op + j) = v;
  }
}

// ===================== depthwise causal conv + GELU ========================
// thread = (bc, d), conv along the 29 high-bin axis. grid (4,256,2).
__global__ __launch_bounds__(256) void dwconv_kernel(const float* __restrict__ Xh,
                                                     const float* __restrict__ dwr,
                                                     const float* __restrict__ dwi,
                                                     float* __restrict__ Gr,
                                                     float* __restrict__ Gi) {
  const int d = blockIdx.x * 256 + threadIdx.x;
  const int bc = blockIdx.y;
  const float* dw = blockIdx.z ? dwi : dwr;
  float* G = blockIdx.z ? Gi : Gr;
  const int imoff = blockIdx.z ? 33 * 1024 : 0;
  float w[7];
#pragma unroll
  for (int j = 0; j < 7; j++) w[j] = dw[d * 7 + j];
  float x[29];
#pragma unroll
  for (int l = 0; l < 29; l++) x[l] = Xh[((long)bc * 66 + 4 + l) * 1024 + imoff + d];
#pragma unroll
  for (int l = 0; l < 29; l++) {
    float y = 0.f;
#pragma unroll
    for (int j = 0; j < 7; j++) {
      int src = l - 6 + j;
      if (src >= 0) y = fmaf(w[j], x[src], y);
    }
    float ge = 0.5f * y * (1.f + erff(y * 0.7071067811865475f));
    G[((long)bc * 29 + l) * 1024 + d] = ge;
  }
}

// ============================ irfft + output ===============================
// thread = (bc, d). Bins 0..3 from Af (alpha-fused low), 4..32 from Xh
// (updated in-place to A_high). Imag of bins 0 and 32 ignored (pocketfft c2r).
__global__ __launch_bounds__(256) void irfft_kernel(const float* __restrict__ Xh,
                                                    const float* __restrict__ Afr,
                                                    const float* __restrict__ Afi,
                                                    float* __restrict__ out) {
  const int d = blockIdx.x * 256 + threadIdx.x;
  const int bc = blockIdx.y;
  const int b = bc >> 6, t0 = (bc & 63) << 2;
  const long afbase = ((long)(b * 256 + t0)) * 1024 + d;
  const long xbase = (long)bc * 66 * 1024 + d;
  const float W = 6.283185307179586f / 64.f;
  float E[32], Od[32];
#pragma unroll
  for (int t = 0; t < 32; t++) { E[t] = 0.f; Od[t] = 0.f; }
  const float R0 = Afr[afbase];
  const float R32 = Xh[xbase + 32 * 1024];
  for (int f = 2; f <= 30; f += 2) {
    float Rf = (f < 4) ? Afr[afbase + (long)f * 1024] : Xh[xbase + (long)f * 1024];
    float If = (f < 4) ? Afi[afbase + (long)f * 1024] : Xh[xbase + (long)(33 + f) * 1024];
    float a = 2.f * Rf, bb = -2.f * If;
    float sd, cd;
    __sincosf(W * f, &sd, &cd);
    float c = 1.f, s = 0.f;
#pragma unroll
    for (int t = 0; t < 32; t++) {
      E[t] = fmaf(a, c, fmaf(bb, s, E[t]));
      float cn = c * cd - s * sd;
      s = s * cd + c * sd;
      c = cn;
    }
  }
  for (int f = 1; f <= 31; f += 2) {
    float Rf = (f < 4) ? Afr[afbase + (long)f * 1024] : Xh[xbase + (long)f * 1024];
    float If = (f < 4) ? Afi[afbase + (long)f * 1024] : Xh[xbase + (long)(33 + f) * 1024];
    float a = 2.f * Rf, bb = -2.f * If;
    float sd, cd;
    __sincosf(W * f, &sd, &cd);
    float c = 1.f, s = 0.f;
#pragma unroll
    for (int t = 0; t < 32; t++) {
      Od[t] = fmaf(a, c, fmaf(bb, s, Od[t]));
      float cn = c * cd - s * sd;
      s = s * cd + c * sd;
      c = cn;
    }
  }
#pragma unroll
  for (int t = 0; t < 32; t++) {
    float base = R0 + ((t & 1) ? -R32 : R32);
    out[((long)(bc * 64 + t)) * 1024 + d] = (base + E[t] + Od[t]) * (1.f / 64.f);
    out[((long)(bc * 64 + t + 32)) * 1024 + d] = (base + E[t] - Od[t]) * (1.f / 64.f);
  }
}

// ============================ launcher =====================================
extern "C" void kernel_launch(void* const* d_in, const int* in_sizes, int n_in,
                              void* d_out, int out_size, void* d_ws, size_t ws_size,
                              hipStream_t stream) {
  const float* hidden = (const float*)d_in[0];
  const float* q_w = (const float*)d_in[1];
  const float* k_w = (const float*)d_in[2];
  const float* v_w = (const float*)d_in[3];
  const float* o_w = (const float*)d_in[4];
  const float* dw_r = (const float*)d_in[5];
  const float* pw_r = (const float*)d_in[6];
  const float* dw_i = (const float*)d_in[7];
  const float* pw_i = (const float*)d_in[8];
  const float* gate_w = (const float*)d_in[9];
  const float* alpha_raw = (const float*)d_in[10];
  float* out = (float*)d_out;

  float* ws = (float*)d_ws;
  float* Xh = ws;                       // 256*66*1024   = 17,301,504
  float* Wqkv = Xh + 17301504;          // 1536*1024     =  1,572,864
  float* QKVr = Wqkv + 1572864;         // 1024*1536
  float* QKVi = QKVr + 1572864;
  float* Or_ = QKVi + 1572864;          // 1024*1024
  float* Oi_ = Or_ + 1048576;
  float* Afr = Oi_ + 1048576;           // 1024*1024
  float* Afi = Afr + 1048576;
  float* gg = Afi + 1048576;            // 256*1024
  float* Gr = gg + 262144;              // 7424*1024
  float* Gi = Gr + 7602176;             // total 41,680,896 floats (~159 MB)

  // 1) rfft of each chunk -> Xh (66 rows per chunk)
  dft_kernel<<<dim3(4, 256), 256, 0, stream>>>(hidden, Xh);
  // 2) concat q/k/v weights -> one N=1536 GEMM
  concat_w<<<1536, 256, 0, stream>>>(q_w, k_w, v_w, Wqkv);
  // 3) QKV projections for real & imag (z-dim)
  mm_kernel<128, 64, AM_XLOW, EP_NONE><<<dim3(8, 24, 2), 256, 0, stream>>>(
      Xh, Xh, 0, Wqkv, Wqkv, 1536, 1024, QKVr, QKVi, Xh, nullptr, nullptr, nullptr);
  // 4) gate = sigmoid((bin0/64) @ gate_w^T)
  mm_kernel<64, 64, AM_CONT, EP_SIGMOID><<<dim3(4, 16, 1), 256, 0, stream>>>(
      Xh, Xh, 66 * 1024, gate_w, gate_w, 1024, 1024, gg, gg, Xh, nullptr, nullptr, nullptr);
  // 5) block-causal GQA attention (real & imag)
  attn_kernel<<<dim3(16, 4, 2), 256, 0, stream>>>(QKVr, QKVi, Or_, Oi_);
  // 6) O projection + alpha*A_low + (1-alpha)*X_low
  mm_kernel<128, 64, AM_CONT, EP_FUSELOW><<<dim3(8, 16, 2), 256, 0, stream>>>(
      Or_, Oi_, 1024, o_w, o_w, 1024, 1024, Afr, Afi, Xh, nullptr, nullptr, alpha_raw);
  // 7) depthwise causal conv + exact GELU on high bins
  dwconv_kernel<<<dim3(4, 256, 2), 256, 0, stream>>>(Xh, dw_r, dw_i, Gr, Gi);
  // 8) pointwise conv + gate + residual, in-place into Xh high rows
  mm_kernel<128, 64, AM_CONT, EP_HIGH><<<dim3(58, 16, 2), 256, 0, stream>>>(
      Gr, Gi, 1024, pw_r, pw_i, 1024, 1024, nullptr, nullptr, Xh, Xh, gg, alpha_raw);
  // 9) irfft -> output
  irfft_kernel<<<dim3(4, 256), 256, 0, stream>>>(Xh, Afr, Afi, out);
}

// Round 2
// 551.039 us; speedup vs baseline: 2.0522x; 2.0522x over previous
//
#include <hip/hip_runtime.h>
#include <math.h>

// ---------------------------------------------------------------------------
// CausalHFPLayer: B=4, N=4096, D=1024, C=64 -> nc=64 chunks/batch, BC=256
// rfft bins M=33, k_low=4, high bins 29. NH=16, NKV=4, HD=64, T=256.
// Round 2: all GEMMs -> bf16 MFMA (16x16x32), fp32 accumulate.
// ---------------------------------------------------------------------------

typedef __bf16 bf16_t;
typedef bf16_t bf16x8 __attribute__((ext_vector_type(8)));
typedef float f32x4 __attribute__((ext_vector_type(4)));

#define EP_NONE 0
#define EP_SIGMOID 1
#define EP_FUSELOW 2
#define EP_HIGH 3

// ============================ DFT (rfft) kernel ============================
// thread = (bc, d). Loads 64 time samples, produces 33 complex bins into Xh
// (fp32), plus bf16 X_low pack [b*256+t][1024] and bf16 chunk-mean.
__global__ __launch_bounds__(256) void dft_kernel(const float* __restrict__ X,
                                                  float* __restrict__ Xh,
                                                  bf16_t* __restrict__ XLr,
                                                  bf16_t* __restrict__ XLi,
                                                  bf16_t* __restrict__ gmean) {
  const int d = blockIdx.x * 256 + threadIdx.x;
  const long bc = blockIdx.y;
  const int b = (int)(bc >> 6), ch = (int)(bc & 63);
  const float* xp = X + (bc * 64) * 1024 + d;
  float x[64];
#pragma unroll
  for (int t = 0; t < 64; t++) x[t] = xp[(long)t * 1024];
#pragma unroll
  for (int t = 0; t < 32; t++) {
    float a = x[t], bb = x[t + 32];
    x[t] = a + bb;
    x[t + 32] = a - bb;
  }
  float* outp = Xh + bc * 66 * 1024 + d;
  const float W = -6.283185307179586f / 64.f;
  for (int f = 0; f <= 32; f += 2) {  // even bins use u = x[0..31]
    float sd, cd;
    __sincosf(W * f, &sd, &cd);
    float c = 1.f, s = 0.f, ar = 0.f, ai = 0.f;
#pragma unroll
    for (int t = 0; t < 32; t++) {
      ar = fmaf(x[t], c, ar);
      ai = fmaf(x[t], s, ai);
      float cn = c * cd - s * sd;
      s = s * cd + c * sd;
      c = cn;
    }
    outp[(long)f * 1024] = ar;
    outp[(long)(33 + f) * 1024] = ai;
    if (f < 4) {
      long xr = ((long)(b * 256 + ch * 4 + f)) * 1024 + d;
      XLr[xr] = (bf16_t)ar;
      XLi[xr] = (bf16_t)ai;
    }
    if (f == 0) gmean[bc * 1024 + d] = (bf16_t)(ar * (1.f / 64.f));
  }
  for (int f = 1; f <= 31; f += 2) {  // odd bins use w = x[32..63]
    float sd, cd;
    __sincosf(W * f, &sd, &cd);
    float c = 1.f, s = 0.f, ar = 0.f, ai = 0.f;
#pragma unroll
    for (int t = 0; t < 32; t++) {
      ar = fmaf(x[32 + t], c, ar);
      ai = fmaf(x[32 + t], s, ai);
      float cn = c * cd - s * sd;
      s = s * cd + c * sd;
      c = cn;
    }
    outp[(long)f * 1024] = ar;
    outp[(long)(33 + f) * 1024] = ai;
    if (f < 4) {
      long xr = ((long)(b * 256 + ch * 4 + f)) * 1024 + d;
      XLr[xr] = (bf16_t)ar;
      XLi[xr] = (bf16_t)ai;
    }
  }
}

// ==================== weight concat / convert to bf16 ======================
__global__ __launch_bounds__(256) void concat_w(const float* __restrict__ qw,
                                                const float* __restrict__ kw,
                                                const float* __restrict__ vw,
                                                bf16_t* __restrict__ W) {
  int i = blockIdx.x * 256 + threadIdx.x;  // float4 index, total 393216
  float4 v;
  if (i < 262144) v = ((const float4*)qw)[i];
  else if (i < 327680) v = ((const float4*)kw)[i - 262144];
  else v = ((const float4*)vw)[i - 327680];
  bf16_t* o = W + (long)i * 4;
  o[0] = (bf16_t)v.x; o[1] = (bf16_t)v.y; o[2] = (bf16_t)v.z; o[3] = (bf16_t)v.w;
}

__global__ __launch_bounds__(256) void cvt_bf16(const float* __restrict__ src,
                                                bf16_t* __restrict__ dst, int n4) {
  int i = blockIdx.x * 256 + threadIdx.x;
  if (i >= n4) return;
  float4 v = ((const float4*)src)[i];
  bf16_t* o = dst + (long)i * 4;
  o[0] = (bf16_t)v.x; o[1] = (bf16_t)v.y; o[2] = (bf16_t)v.z; o[3] = (bf16_t)v.w;
}

// ============================ bf16 MFMA GEMM ===============================
// C[M,N] = A[M,K] @ B[N,K]^T. A,B bf16 row-major (K contiguous). 128x128
// block tile, BK=32, 4 waves in 2x2, each wave 64x64 via 4x4 mfma 16x16x32.
template <int EMODE>
__global__ __launch_bounds__(256) void mmbf_kernel(
    const bf16_t* __restrict__ A0, const bf16_t* __restrict__ A1,
    const bf16_t* __restrict__ B0, const bf16_t* __restrict__ B1,
    int N, int K,
    float* __restrict__ C0, float* __restrict__ C1,
    const float* __restrict__ Xh, float* __restrict__ XhMut,
    const float* __restrict__ gate, const float* __restrict__ alpha_ptr) {
  constexpr int BM = 128, BN = 128, BK = 32, LDK = BK + 8;  // pad: 2-way only
  __shared__ bf16_t As[BM * LDK];
  __shared__ bf16_t Bs[BN * LDK];
  const int z = blockIdx.z;
  const bf16_t* A = z ? A1 : A0;
  const bf16_t* B = z ? B1 : B0;
  float* C = z ? C1 : C0;
  const int imoff = z ? 33 * 1024 : 0;
  const int tid = threadIdx.x;
  const int lane = tid & 63;
  const int wave = tid >> 6;
  const int wm = (wave & 1) * 64, wn = (wave >> 1) * 64;
  const int m0 = blockIdx.x * BM, n0 = blockIdx.y * BN;
  const int srow = tid >> 2, sc8 = (tid & 3) * 8;  // staging: rows 0..63 (+64)
  const int q = lane >> 4, mr = lane & 15;

  f32x4 acc[4][4];
#pragma unroll
  for (int i = 0; i < 4; i++)
#pragma unroll
    for (int j = 0; j < 4; j++) acc[i][j] = (f32x4){0.f, 0.f, 0.f, 0.f};

  for (int kb = 0; kb < K; kb += BK) {
#pragma unroll
    for (int it = 0; it < 2; it++) {
      int row = srow + it * 64;
      bf16x8 va = *(const bf16x8*)(A + (long)(m0 + row) * K + kb + sc8);
      *(bf16x8*)&As[row * LDK + sc8] = va;
      bf16x8 vb = *(const bf16x8*)(B + (long)(n0 + row) * K + kb + sc8);
      *(bf16x8*)&Bs[row * LDK + sc8] = vb;
    }
    __syncthreads();
    bf16x8 af[4], bfr[4];
#pragma unroll
    for (int mi = 0; mi < 4; mi++)
      af[mi] = *(const bf16x8*)&As[(wm + mi * 16 + mr) * LDK + q * 8];
#pragma unroll
    for (int ni = 0; ni < 4; ni++)
      bfr[ni] = *(const bf16x8*)&Bs[(wn + ni * 16 + mr) * LDK + q * 8];
#pragma unroll
    for (int mi = 0; mi < 4; mi++)
#pragma unroll
      for (int ni = 0; ni < 4; ni++)
        acc[mi][ni] = __builtin_amdgcn_mfma_f32_16x16x32_bf16(
            af[mi], bfr[ni], acc[mi][ni], 0, 0, 0);
    __syncthreads();
  }

  float alpha = 0.f;
  if constexpr (EMODE == EP_FUSELOW) alpha = 1.f / (1.f + __expf(-alpha_ptr[0]));
#pragma unroll
  for (int mi = 0; mi < 4; mi++) {
#pragma unroll
    for (int ni = 0; ni < 4; ni++) {
      int col = n0 + wn + ni * 16 + (lane & 15);
      int rbase = m0 + wm + mi * 16 + (lane >> 4) * 4;
#pragma unroll
      for (int r = 0; r < 4; r++) {
        int row = rbase + r;
        float val = acc[mi][ni][r];
        if constexpr (EMODE == EP_NONE) {
          C[(long)row * N + col] = val;
        } else if constexpr (EMODE == EP_SIGMOID) {
          C[(long)row * N + col] = 1.f / (1.f + __expf(-val));
        } else if constexpr (EMODE == EP_FUSELOW) {
          int b = row >> 8, t = row & 255;
          long x = ((long)((b << 6) + (t >> 2)) * 66 + (t & 3)) * 1024 + imoff + col;
          C[(long)row * 1024 + col] = alpha * val + (1.f - alpha) * Xh[x];
        } else {  // EP_HIGH
          int bc = row / 29, l = row - bc * 29;
          long x = ((long)bc * 66 + 4 + l) * 1024 + imoff + col;
          XhMut[x] = fmaf(val, gate[(long)bc * 1024 + col], Xh[x]);
        }
      }
    }
  }
}

// ============================ attention ====================================
// grid (NH, B, 2). block 256 = one q row per thread. Online softmax. Writes
// bf16 O for the bf16 O-projection GEMM.
__global__ __launch_bounds__(256) void attn_kernel(const float* __restrict__ QKVr,
                                                   const float* __restrict__ QKVi,
                                                   bf16_t* __restrict__ Or_,
                                                   bf16_t* __restrict__ Oi_) {
  const int h = blockIdx.x, b = blockIdx.y;
  const float* QKV = blockIdx.z ? QKVi : QKVr;
  bf16_t* O = blockIdx.z ? Oi_ : Or_;
  const int kvh = h >> 2;
  const int tid = threadIdx.x;  // q row
  __shared__ float Ks[64 * 64];
  __shared__ float Vs[64 * 64];

  float qv[64];
  const float* qp = QKV + ((long)(b * 256 + tid)) * 1536 + h * 64;
#pragma unroll
  for (int j = 0; j < 64; j += 4) {
    float4 v = *(const float4*)(qp + j);
    qv[j] = v.x; qv[j + 1] = v.y; qv[j + 2] = v.z; qv[j + 3] = v.w;
  }
  float acc[64];
#pragma unroll
  for (int j = 0; j < 64; j++) acc[j] = 0.f;
  float m = -1e30f, l = 0.f;
  const int kend = ((tid >> 2) + 1) << 2;  // (chunk+1)*4

  for (int tile = 0; tile < 4; tile++) {
#pragma unroll
    for (int it = 0; it < 4; it++) {
      int idx = tid + it * 256;  // 0..1023
      int tr = idx >> 4;
      int j4 = (idx & 15) << 2;
      const float* base = QKV + ((long)(b * 256 + tile * 64 + tr)) * 1536 + kvh * 64;
      *(float4*)&Ks[tr * 64 + j4] = *(const float4*)(base + 1024 + j4);
      *(float4*)&Vs[tr * 64 + j4] = *(const float4*)(base + 1280 + j4);
    }
    __syncthreads();
    int cnt = kend - tile * 64;
    cnt = cnt > 64 ? 64 : cnt;
    for (int kp = 0; kp < cnt; kp++) {
      const float* kr = &Ks[kp * 64];
      float s = 0.f;
#pragma unroll
      for (int j = 0; j < 64; j++) s = fmaf(qv[j], kr[j], s);
      s *= 0.125f;
      float mn = fmaxf(m, s);
      float sc = __expf(m - mn);
      float p = __expf(s - mn);
      l = l * sc + p;
      m = mn;
      const float* vr = &Vs[kp * 64];
#pragma unroll
      for (int j = 0; j < 64; j++) acc[j] = fmaf(acc[j], sc, p * vr[j]);
    }
    __syncthreads();
  }
  float inv = 1.f / l;
  bf16_t* op = O + ((long)(b * 256 + tid)) * 1024 + h * 64;
#pragma unroll
  for (int j = 0; j < 64; j += 8) {
    bf16x8 v;
#pragma unroll
    for (int u = 0; u < 8; u++) v[u] = (bf16_t)(acc[j + u] * inv);
    *(bf16x8*)(op + j) = v;
  }
}

// ===================== depthwise causal conv + GELU ========================
// thread = (bc, d), conv along the 29 high-bin axis. grid (4,256,2). bf16 out.
__global__ __launch_bounds__(256) void dwconv_kernel(const float* __restrict__ Xh,
                                                     const float* __restrict__ dwr,
                                                     const float* __restrict__ dwi,
                                                     bf16_t* __restrict__ Gr,
                                                     bf16_t* __restrict__ Gi) {
  const int d = blockIdx.x * 256 + threadIdx.x;
  const int bc = blockIdx.y;
  const float* dw = blockIdx.z ? dwi : dwr;
  bf16_t* G = blockIdx.z ? Gi : Gr;
  const int imoff = blockIdx.z ? 33 * 1024 : 0;
  float w[7];
#pragma unroll
  for (int j = 0; j < 7; j++) w[j] = dw[d * 7 + j];
  float x[29];
#pragma unroll
  for (int l = 0; l < 29; l++) x[l] = Xh[((long)bc * 66 + 4 + l) * 1024 + imoff + d];
#pragma unroll
  for (int l = 0; l < 29; l++) {
    float y = 0.f;
#pragma unroll
    for (int j = 0; j < 7; j++) {
      int src = l - 6 + j;
      if (src >= 0) y = fmaf(w[j], x[src], y);
    }
    float ge = 0.5f * y * (1.f + erff(y * 0.7071067811865475f));
    G[((long)bc * 29 + l) * 1024 + d] = (bf16_t)ge;
  }
}

// ============================ irfft + output ===============================
__global__ __launch_bounds__(256) void irfft_kernel(const float* __restrict__ Xh,
                                                    const float* __restrict__ Afr,
                                                    const float* __restrict__ Afi,
                                                    float* __restrict__ out) {
  const int d = blockIdx.x * 256 + threadIdx.x;
  const int bc = blockIdx.y;
  const int b = bc >> 6, t0 = (bc & 63) << 2;
  const long afbase = ((long)(b * 256 + t0)) * 1024 + d;
  const long xbase = (long)bc * 66 * 1024 + d;
  const float W = 6.283185307179586f / 64.f;
  float E[32], Od[32];
#pragma unroll
  for (int t = 0; t < 32; t++) { E[t] = 0.f; Od[t] = 0.f; }
  const float R0 = Afr[afbase];
  const float R32 = Xh[xbase + 32 * 1024];
  for (int f = 2; f <= 30; f += 2) {
    float Rf = (f < 4) ? Afr[afbase + (long)f * 1024] : Xh[xbase + (long)f * 1024];
    float If = (f < 4) ? Afi[afbase + (long)f * 1024] : Xh[xbase + (long)(33 + f) * 1024];
    float a = 2.f * Rf, bb = -2.f * If;
    float sd, cd;
    __sincosf(W * f, &sd, &cd);
    float c = 1.f, s = 0.f;
#pragma unroll
    for (int t = 0; t < 32; t++) {
      E[t] = fmaf(a, c, fmaf(bb, s, E[t]));
      float cn = c * cd - s * sd;
      s = s * cd + c * sd;
      c = cn;
    }
  }
  for (int f = 1; f <= 31; f += 2) {
    float Rf = (f < 4) ? Afr[afbase + (long)f * 1024] : Xh[xbase + (long)f * 1024];
    float If = (f < 4) ? Afi[afbase + (long)f * 1024] : Xh[xbase + (long)(33 + f) * 1024];
    float a = 2.f * Rf, bb = -2.f * If;
    float sd, cd;
    __sincosf(W * f, &sd, &cd);
    float c = 1.f, s = 0.f;
#pragma unroll
    for (int t = 0; t < 32; t++) {
      Od[t] = fmaf(a, c, fmaf(bb, s, Od[t]));
      float cn = c * cd - s * sd;
      s = s * cd + c * sd;
      c = cn;
    }
  }
#pragma unroll
  for (int t = 0; t < 32; t++) {
    float base = R0 + ((t & 1) ? -R32 : R32);
    out[((long)(bc * 64 + t)) * 1024 + d] = (base + E[t] + Od[t]) * (1.f / 64.f);
    out[((long)(bc * 64 + t + 32)) * 1024 + d] = (base + E[t] - Od[t]) * (1.f / 64.f);
  }
}

// ============================ launcher =====================================
extern "C" void kernel_launch(void* const* d_in, const int* in_sizes, int n_in,
                              void* d_out, int out_size, void* d_ws, size_t ws_size,
                              hipStream_t stream) {
  const float* hidden = (const float*)d_in[0];
  const float* q_w = (const float*)d_in[1];
  const float* k_w = (const float*)d_in[2];
  const float* v_w = (const float*)d_in[3];
  const float* o_w = (const float*)d_in[4];
  const float* dw_r = (const float*)d_in[5];
  const float* pw_r = (const float*)d_in[6];
  const float* dw_i = (const float*)d_in[7];
  const float* pw_i = (const float*)d_in[8];
  const float* gate_w = (const float*)d_in[9];
  const float* alpha_raw = (const float*)d_in[10];
  float* out = (float*)d_out;

  float* ws = (float*)d_ws;
  // fp32 region
  float* Xh = ws;                        // 256*66*1024 = 17,301,504
  float* QKVr = Xh + 17301504;           // 1024*1536
  float* QKVi = QKVr + 1572864;
  float* Afr = QKVi + 1572864;           // 1024*1024
  float* Afi = Afr + 1048576;
  float* gg = Afi + 1048576;             // 256*1024
  // bf16 region
  bf16_t* bws = (bf16_t*)(gg + 262144);
  bf16_t* Wqkv_b = bws;                  // 1536*1024
  bf16_t* ow_b = Wqkv_b + 1572864;       // 1024*1024
  bf16_t* gw_b = ow_b + 1048576;
  bf16_t* pwr_b = gw_b + 1048576;
  bf16_t* pwi_b = pwr_b + 1048576;
  bf16_t* XLr = pwi_b + 1048576;         // 1024*1024
  bf16_t* XLi = XLr + 1048576;
  bf16_t* gmean = XLi + 1048576;         // 256*1024
  bf16_t* Obr = gmean + 262144;          // 1024*1024
  bf16_t* Obi = Obr + 1048576;
  bf16_t* Gr = Obi + 1048576;            // 7424*1024
  bf16_t* Gi = Gr + 7602176;             // total ~142 MB

  // 1) rfft of each chunk -> Xh fp32 + bf16 X_low pack + bf16 chunk-mean
  dft_kernel<<<dim3(4, 256), 256, 0, stream>>>(hidden, Xh, XLr, XLi, gmean);
  // 2) weights -> bf16
  concat_w<<<1536, 256, 0, stream>>>(q_w, k_w, v_w, Wqkv_b);
  cvt_bf16<<<1024, 256, 0, stream>>>(o_w, ow_b, 262144);
  cvt_bf16<<<1024, 256, 0, stream>>>(gate_w, gw_b, 262144);
  cvt_bf16<<<1024, 256, 0, stream>>>(pw_r, pwr_b, 262144);
  cvt_bf16<<<1024, 256, 0, stream>>>(pw_i, pwi_b, 262144);
  // 3) QKV projections (real & imag via z)
  mmbf_kernel<EP_NONE><<<dim3(8, 12, 2), 256, 0, stream>>>(
      XLr, XLi, Wqkv_b, Wqkv_b, 1536, 1024, QKVr, QKVi, nullptr, nullptr,
      nullptr, nullptr);
  // 4) gate = sigmoid(mean @ gate_w^T)  (gmean already /64)
  mmbf_kernel<EP_SIGMOID><<<dim3(2, 8, 1), 256, 0, stream>>>(
      gmean, gmean, gw_b, gw_b, 1024, 1024, gg, gg, nullptr, nullptr,
      nullptr, nullptr);
  // 5) block-causal GQA attention (real & imag), bf16 O out
  attn_kernel<<<dim3(16, 4, 2), 256, 0, stream>>>(QKVr, QKVi, Obr, Obi);
  // 6) O projection + alpha*A_low + (1-alpha)*X_low
  mmbf_kernel<EP_FUSELOW><<<dim3(8, 8, 2), 256, 0, stream>>>(
      Obr, Obi, ow_b, ow_b, 1024, 1024, Afr, Afi, Xh, nullptr, nullptr,
      alpha_raw);
  // 7) depthwise causal conv + exact GELU on high bins, bf16 out
  dwconv_kernel<<<dim3(4, 256, 2), 256, 0, stream>>>(Xh, dw_r, dw_i, Gr, Gi);
  // 8) pointwise conv + gate + residual, in-place into Xh high rows
  mmbf_kernel<EP_HIGH><<<dim3(58, 8, 2), 256, 0, stream>>>(
      Gr, Gi, pwr_b, pwi_b, 1024, 1024, nullptr, nullptr, Xh, Xh, gg,
      alpha_raw);
  // 9) irfft -> output
  irfft_kernel<<<dim3(4, 256), 256, 0, stream>>>(Xh, Afr, Afi, out);
}

// Round 3
// 413.238 us; speedup vs baseline: 2.7365x; 1.3335x over previous
//
#include <hip/hip_runtime.h>
#include <math.h>

// ---------------------------------------------------------------------------
// CausalHFPLayer: B=4, N=4096, D=1024, C=64 -> nc=64 chunks/batch, BC=256
// rfft bins M=33, k_low=4, high bins 29. NH=16, NKV=4, HD=64, T=256.
// Round 3: MFMA flash attention (bf16), QKV GEMM emits bf16 directly.
// ---------------------------------------------------------------------------

typedef __bf16 bf16_t;
typedef bf16_t bf16x8 __attribute__((ext_vector_type(8)));
typedef float f32x4 __attribute__((ext_vector_type(4)));

#define EP_NONE 0
#define EP_SIGMOID 1
#define EP_FUSELOW 2
#define EP_HIGH 3

// ============================ DFT (rfft) kernel ============================
__global__ __launch_bounds__(256) void dft_kernel(const float* __restrict__ X,
                                                  float* __restrict__ Xh,
                                                  bf16_t* __restrict__ XLr,
                                                  bf16_t* __restrict__ XLi,
                                                  bf16_t* __restrict__ gmean) {
  const int d = blockIdx.x * 256 + threadIdx.x;
  const long bc = blockIdx.y;
  const int b = (int)(bc >> 6), ch = (int)(bc & 63);
  const float* xp = X + (bc * 64) * 1024 + d;
  float x[64];
#pragma unroll
  for (int t = 0; t < 64; t++) x[t] = xp[(long)t * 1024];
#pragma unroll
  for (int t = 0; t < 32; t++) {
    float a = x[t], bb = x[t + 32];
    x[t] = a + bb;
    x[t + 32] = a - bb;
  }
  float* outp = Xh + bc * 66 * 1024 + d;
  const float W = -6.283185307179586f / 64.f;
  for (int f = 0; f <= 32; f += 2) {
    float sd, cd;
    __sincosf(W * f, &sd, &cd);
    float c = 1.f, s = 0.f, ar = 0.f, ai = 0.f;
#pragma unroll
    for (int t = 0; t < 32; t++) {
      ar = fmaf(x[t], c, ar);
      ai = fmaf(x[t], s, ai);
      float cn = c * cd - s * sd;
      s = s * cd + c * sd;
      c = cn;
    }
    outp[(long)f * 1024] = ar;
    outp[(long)(33 + f) * 1024] = ai;
    if (f < 4) {
      long xr = ((long)(b * 256 + ch * 4 + f)) * 1024 + d;
      XLr[xr] = (bf16_t)ar;
      XLi[xr] = (bf16_t)ai;
    }
    if (f == 0) gmean[bc * 1024 + d] = (bf16_t)(ar * (1.f / 64.f));
  }
  for (int f = 1; f <= 31; f += 2) {
    float sd, cd;
    __sincosf(W * f, &sd, &cd);
    float c = 1.f, s = 0.f, ar = 0.f, ai = 0.f;
#pragma unroll
    for (int t = 0; t < 32; t++) {
      ar = fmaf(x[32 + t], c, ar);
      ai = fmaf(x[32 + t], s, ai);
      float cn = c * cd - s * sd;
      s = s * cd + c * sd;
      c = cn;
    }
    outp[(long)f * 1024] = ar;
    outp[(long)(33 + f) * 1024] = ai;
    if (f < 4) {
      long xr = ((long)(b * 256 + ch * 4 + f)) * 1024 + d;
      XLr[xr] = (bf16_t)ar;
      XLi[xr] = (bf16_t)ai;
    }
  }
}

// ==================== weight concat / convert to bf16 ======================
__global__ __launch_bounds__(256) void concat_w(const float* __restrict__ qw,
                                                const float* __restrict__ kw,
                                                const float* __restrict__ vw,
                                                bf16_t* __restrict__ W) {
  int i = blockIdx.x * 256 + threadIdx.x;  // float4 index, total 393216
  float4 v;
  if (i < 262144) v = ((const float4*)qw)[i];
  else if (i < 327680) v = ((const float4*)kw)[i - 262144];
  else v = ((const float4*)vw)[i - 327680];
  bf16_t* o = W + (long)i * 4;
  o[0] = (bf16_t)v.x; o[1] = (bf16_t)v.y; o[2] = (bf16_t)v.z; o[3] = (bf16_t)v.w;
}

__global__ __launch_bounds__(256) void cvt_bf16(const float* __restrict__ src,
                                                bf16_t* __restrict__ dst, int n4) {
  int i = blockIdx.x * 256 + threadIdx.x;
  if (i >= n4) return;
  float4 v = ((const float4*)src)[i];
  bf16_t* o = dst + (long)i * 4;
  o[0] = (bf16_t)v.x; o[1] = (bf16_t)v.y; o[2] = (bf16_t)v.z; o[3] = (bf16_t)v.w;
}

// ============================ bf16 MFMA GEMM ===============================
// C[M,N] = A[M,K] @ B[N,K]^T. 128x128 tile, BK=32, 2x2 waves x 4x4 mfma.
// EP_NONE writes bf16 output; others fp32 / in-place.
template <int EMODE>
__global__ __launch_bounds__(256) void mmbf_kernel(
    const bf16_t* __restrict__ A0, const bf16_t* __restrict__ A1,
    const bf16_t* __restrict__ B0, const bf16_t* __restrict__ B1,
    int N, int K,
    void* __restrict__ C0v, void* __restrict__ C1v,
    const float* __restrict__ Xh, float* __restrict__ XhMut,
    const float* __restrict__ gate, const float* __restrict__ alpha_ptr) {
  constexpr int BM = 128, BN = 128, BK = 32, LDK = BK + 8;  // pad: 2-way only
  __shared__ bf16_t As[BM * LDK];
  __shared__ bf16_t Bs[BN * LDK];
  const int z = blockIdx.z;
  const bf16_t* A = z ? A1 : A0;
  const bf16_t* B = z ? B1 : B0;
  void* Cv = z ? C1v : C0v;
  const int imoff = z ? 33 * 1024 : 0;
  const int tid = threadIdx.x;
  const int lane = tid & 63;
  const int wave = tid >> 6;
  const int wm = (wave & 1) * 64, wn = (wave >> 1) * 64;
  const int m0 = blockIdx.x * BM, n0 = blockIdx.y * BN;
  const int srow = tid >> 2, sc8 = (tid & 3) * 8;
  const int q = lane >> 4, mr = lane & 15;

  f32x4 acc[4][4];
#pragma unroll
  for (int i = 0; i < 4; i++)
#pragma unroll
    for (int j = 0; j < 4; j++) acc[i][j] = (f32x4){0.f, 0.f, 0.f, 0.f};

  for (int kb = 0; kb < K; kb += BK) {
#pragma unroll
    for (int it = 0; it < 2; it++) {
      int row = srow + it * 64;
      bf16x8 va = *(const bf16x8*)(A + (long)(m0 + row) * K + kb + sc8);
      *(bf16x8*)&As[row * LDK + sc8] = va;
      bf16x8 vb = *(const bf16x8*)(B + (long)(n0 + row) * K + kb + sc8);
      *(bf16x8*)&Bs[row * LDK + sc8] = vb;
    }
    __syncthreads();
    bf16x8 af[4], bfr[4];
#pragma unroll
    for (int mi = 0; mi < 4; mi++)
      af[mi] = *(const bf16x8*)&As[(wm + mi * 16 + mr) * LDK + q * 8];
#pragma unroll
    for (int ni = 0; ni < 4; ni++)
      bfr[ni] = *(const bf16x8*)&Bs[(wn + ni * 16 + mr) * LDK + q * 8];
#pragma unroll
    for (int mi = 0; mi < 4; mi++)
#pragma unroll
      for (int ni = 0; ni < 4; ni++)
        acc[mi][ni] = __builtin_amdgcn_mfma_f32_16x16x32_bf16(
            af[mi], bfr[ni], acc[mi][ni], 0, 0, 0);
    __syncthreads();
  }

  float alpha = 0.f;
  if constexpr (EMODE == EP_FUSELOW) alpha = 1.f / (1.f + __expf(-alpha_ptr[0]));
#pragma unroll
  for (int mi = 0; mi < 4; mi++) {
#pragma unroll
    for (int ni = 0; ni < 4; ni++) {
      int col = n0 + wn + ni * 16 + mr;
      int rbase = m0 + wm + mi * 16 + q * 4;
#pragma unroll
      for (int r = 0; r < 4; r++) {
        int row = rbase + r;
        float val = acc[mi][ni][r];
        if constexpr (EMODE == EP_NONE) {
          ((bf16_t*)Cv)[(long)row * N + col] = (bf16_t)val;
        } else if constexpr (EMODE == EP_SIGMOID) {
          ((float*)Cv)[(long)row * N + col] = 1.f / (1.f + __expf(-val));
        } else if constexpr (EMODE == EP_FUSELOW) {
          int b = row >> 8, t = row & 255;
          long x = ((long)((b << 6) + (t >> 2)) * 66 + (t & 3)) * 1024 + imoff + col;
          ((float*)Cv)[(long)row * 1024 + col] = alpha * val + (1.f - alpha) * Xh[x];
        } else {  // EP_HIGH
          int bc = row / 29, l = row - bc * 29;
          long x = ((long)bc * 66 + 4 + l) * 1024 + imoff + col;
          XhMut[x] = fmaf(val, gate[(long)bc * 1024 + col], Xh[x]);
        }
      }
    }
  }
}

// ====================== MFMA flash attention ===============================
// grid (NH=16, B*4 qtiles=16, 2). block 256 = 4 waves; wave w owns q rows
// [qt*64 + w*16, +16). K-tiles of 64 keys staged in LDS (shared), V staged
// transposed. Online softmax per row; P -> LDS -> A-layout for PV (m120).
// Block-causal mask (chunk=4): kt<qt fully visible, kt==qt element-masked.
__global__ __launch_bounds__(256) void attn_mfma(const bf16_t* __restrict__ QKVr,
                                                 const bf16_t* __restrict__ QKVi,
                                                 bf16_t* __restrict__ Or_,
                                                 bf16_t* __restrict__ Oi_) {
  const int h = blockIdx.x;
  const int b = blockIdx.y >> 2, qt = blockIdx.y & 3;
  const bf16_t* QKV = blockIdx.z ? QKVi : QKVr;
  bf16_t* O = blockIdx.z ? Oi_ : Or_;
  const int kvh = h >> 2;
  const int tid = threadIdx.x;
  const int lane = tid & 63, wave = tid >> 6;
  const int mr = lane & 15, q4 = lane >> 4;

  __shared__ bf16_t Ks[64 * 72];       // [key][d] pad 8
  __shared__ bf16_t Vt[64 * 72];       // [d][key] pad 8
  __shared__ bf16_t Ps[4][16 * 72];    // per wave [qrow][key] pad 8

  // Q fragments (A-layout) for this wave's 16 q rows, HD=64 -> 2 k-steps
  bf16x8 af[2];
  {
    const bf16_t* qp =
        QKV + (long)(b * 256 + qt * 64 + wave * 16 + mr) * 1536 + h * 64;
    af[0] = *(const bf16x8*)(qp + q4 * 8);
    af[1] = *(const bf16x8*)(qp + 32 + q4 * 8);
  }
  f32x4 Oacc[4];
#pragma unroll
  for (int ni = 0; ni < 4; ni++) Oacc[ni] = (f32x4){0.f, 0.f, 0.f, 0.f};
  float mrow[4], lrow[4];
#pragma unroll
  for (int r = 0; r < 4; r++) { mrow[r] = -1e30f; lrow[r] = 0.f; }

  for (int kt = 0; kt <= qt; kt++) {
    // ---- stage K tile and transposed V tile ----
#pragma unroll
    for (int it = 0; it < 2; it++) {
      int idx = tid + it * 256;  // 0..511
      int key = idx >> 3, dg = idx & 7;
      const bf16_t* kp = QKV + (long)(b * 256 + kt * 64 + key) * 1536 + 1024 +
                         kvh * 64 + dg * 8;
      *(bf16x8*)&Ks[key * 72 + dg * 8] = *(const bf16x8*)kp;
      bf16x8 vv = *(const bf16x8*)(kp + 256);
#pragma unroll
      for (int j = 0; j < 8; j++) Vt[(dg * 8 + j) * 72 + key] = vv[j];
    }
    __syncthreads();

    // ---- S = Q K^T (16 q rows x 64 keys) ----
    f32x4 S[4];
#pragma unroll
    for (int ni = 0; ni < 4; ni++) {
      S[ni] = (f32x4){0.f, 0.f, 0.f, 0.f};
#pragma unroll
      for (int s = 0; s < 2; s++) {
        bf16x8 kb = *(const bf16x8*)&Ks[(ni * 16 + mr) * 72 + s * 32 + q4 * 8];
        S[ni] = __builtin_amdgcn_mfma_f32_16x16x32_bf16(af[s], kb, S[ni], 0, 0, 0);
      }
    }
    // ---- scale + causal mask (diagonal tile only) ----
#pragma unroll
    for (int ni = 0; ni < 4; ni++) {
#pragma unroll
      for (int r = 0; r < 4; r++) {
        float v = S[ni][r] * 0.125f;
        if (kt == qt) {
          int qrow = wave * 16 + q4 * 4 + r;   // within 64-row q block
          int kcol = ni * 16 + mr;             // within 64-key k block
          if ((qrow >> 2) < (kcol >> 2)) v = -1e30f;
        }
        S[ni][r] = v;
      }
    }
    // ---- online softmax + P to LDS + O rescale ----
#pragma unroll
    for (int r = 0; r < 4; r++) {
      float mx = fmaxf(fmaxf(S[0][r], S[1][r]), fmaxf(S[2][r], S[3][r]));
#pragma unroll
      for (int off = 1; off < 16; off <<= 1) mx = fmaxf(mx, __shfl_xor(mx, off));
      float mn = fmaxf(mrow[r], mx);
      float sc = __expf(mrow[r] - mn);
      mrow[r] = mn;
      float rs = 0.f;
#pragma unroll
      for (int ni = 0; ni < 4; ni++) {
        float p = __expf(S[ni][r] - mn);
        rs += p;
        Ps[wave][(q4 * 4 + r) * 72 + ni * 16 + mr] = (bf16_t)p;
      }
#pragma unroll
      for (int off = 1; off < 16; off <<= 1) rs += __shfl_xor(rs, off);
      lrow[r] = lrow[r] * sc + rs;
#pragma unroll
      for (int ni = 0; ni < 4; ni++) Oacc[ni][r] *= sc;
    }
    // ---- O += P V  (P from LDS in A-layout, V^T as B operand) ----
    bf16x8 pa[2];
    pa[0] = *(const bf16x8*)&Ps[wave][mr * 72 + q4 * 8];
    pa[1] = *(const bf16x8*)&Ps[wave][mr * 72 + 32 + q4 * 8];
#pragma unroll
    for (int ni = 0; ni < 4; ni++) {
#pragma unroll
      for (int s = 0; s < 2; s++) {
        bf16x8 vb = *(const bf16x8*)&Vt[(ni * 16 + mr) * 72 + s * 32 + q4 * 8];
        Oacc[ni] = __builtin_amdgcn_mfma_f32_16x16x32_bf16(pa[s], vb, Oacc[ni], 0, 0, 0);
      }
    }
    __syncthreads();
  }

  // ---- epilogue: O /= l, write bf16 ----
#pragma unroll
  for (int r = 0; r < 4; r++) {
    float inv = 1.f / lrow[r];
    long row = b * 256 + qt * 64 + wave * 16 + q4 * 4 + r;
#pragma unroll
    for (int ni = 0; ni < 4; ni++)
      O[row * 1024 + h * 64 + ni * 16 + mr] = (bf16_t)(Oacc[ni][r] * inv);
  }
}

// ===================== depthwise causal conv + GELU ========================
__global__ __launch_bounds__(256) void dwconv_kernel(const float* __restrict__ Xh,
                                                     const float* __restrict__ dwr,
                                                     const float* __restrict__ dwi,
                                                     bf16_t* __restrict__ Gr,
                                                     bf16_t* __restrict__ Gi) {
  const int d = blockIdx.x * 256 + threadIdx.x;
  const int bc = blockIdx.y;
  const float* dw = blockIdx.z ? dwi : dwr;
  bf16_t* G = blockIdx.z ? Gi : Gr;
  const int imoff = blockIdx.z ? 33 * 1024 : 0;
  float w[7];
#pragma unroll
  for (int j = 0; j < 7; j++) w[j] = dw[d * 7 + j];
  float x[29];
#pragma unroll
  for (int l = 0; l < 29; l++) x[l] = Xh[((long)bc * 66 + 4 + l) * 1024 + imoff + d];
#pragma unroll
  for (int l = 0; l < 29; l++) {
    float y = 0.f;
#pragma unroll
    for (int j = 0; j < 7; j++) {
      int src = l - 6 + j;
      if (src >= 0) y = fmaf(w[j], x[src], y);
    }
    float ge = 0.5f * y * (1.f + erff(y * 0.7071067811865475f));
    G[((long)bc * 29 + l) * 1024 + d] = (bf16_t)ge;
  }
}

// ============================ irfft + output ===============================
__global__ __launch_bounds__(256) void irfft_kernel(const float* __restrict__ Xh,
                                                    const float* __restrict__ Afr,
                                                    const float* __restrict__ Afi,
                                                    float* __restrict__ out) {
  const int d = blockIdx.x * 256 + threadIdx.x;
  const int bc = blockIdx.y;
  const int b = bc >> 6, t0 = (bc & 63) << 2;
  const long afbase = ((long)(b * 256 + t0)) * 1024 + d;
  const long xbase = (long)bc * 66 * 1024 + d;
  const float W = 6.283185307179586f / 64.f;
  float E[32], Od[32];
#pragma unroll
  for (int t = 0; t < 32; t++) { E[t] = 0.f; Od[t] = 0.f; }
  const float R0 = Afr[afbase];
  const float R32 = Xh[xbase + 32 * 1024];
  for (int f = 2; f <= 30; f += 2) {
    float Rf = (f < 4) ? Afr[afbase + (long)f * 1024] : Xh[xbase + (long)f * 1024];
    float If = (f < 4) ? Afi[afbase + (long)f * 1024] : Xh[xbase + (long)(33 + f) * 1024];
    float a = 2.f * Rf, bb = -2.f * If;
    float sd, cd;
    __sincosf(W * f, &sd, &cd);
    float c = 1.f, s = 0.f;
#pragma unroll
    for (int t = 0; t < 32; t++) {
      E[t] = fmaf(a, c, fmaf(bb, s, E[t]));
      float cn = c * cd - s * sd;
      s = s * cd + c * sd;
      c = cn;
    }
  }
  for (int f = 1; f <= 31; f += 2) {
    float Rf = (f < 4) ? Afr[afbase + (long)f * 1024] : Xh[xbase + (long)f * 1024];
    float If = (f < 4) ? Afi[afbase + (long)f * 1024] : Xh[xbase + (long)(33 + f) * 1024];
    float a = 2.f * Rf, bb = -2.f * If;
    float sd, cd;
    __sincosf(W * f, &sd, &cd);
    float c = 1.f, s = 0.f;
#pragma unroll
    for (int t = 0; t < 32; t++) {
      Od[t] = fmaf(a, c, fmaf(bb, s, Od[t]));
      float cn = c * cd - s * sd;
      s = s * cd + c * sd;
      c = cn;
    }
  }
#pragma unroll
  for (int t = 0; t < 32; t++) {
    float base = R0 + ((t & 1) ? -R32 : R32);
    out[((long)(bc * 64 + t)) * 1024 + d] = (base + E[t] + Od[t]) * (1.f / 64.f);
    out[((long)(bc * 64 + t + 32)) * 1024 + d] = (base + E[t] - Od[t]) * (1.f / 64.f);
  }
}

// ============================ launcher =====================================
extern "C" void kernel_launch(void* const* d_in, const int* in_sizes, int n_in,
                              void* d_out, int out_size, void* d_ws, size_t ws_size,
                              hipStream_t stream) {
  const float* hidden = (const float*)d_in[0];
  const float* q_w = (const float*)d_in[1];
  const float* k_w = (const float*)d_in[2];
  const float* v_w = (const float*)d_in[3];
  const float* o_w = (const float*)d_in[4];
  const float* dw_r = (const float*)d_in[5];
  const float* pw_r = (const float*)d_in[6];
  const float* dw_i = (const float*)d_in[7];
  const float* pw_i = (const float*)d_in[8];
  const float* gate_w = (const float*)d_in[9];
  const float* alpha_raw = (const float*)d_in[10];
  float* out = (float*)d_out;

  float* ws = (float*)d_ws;
  // fp32 region
  float* Xh = ws;                        // 256*66*1024 = 17,301,504
  float* Afr = Xh + 17301504;            // 1024*1024
  float* Afi = Afr + 1048576;
  float* gg = Afi + 1048576;             // 256*1024
  // bf16 region
  bf16_t* bws = (bf16_t*)(gg + 262144);
  bf16_t* Wqkv_b = bws;                  // 1536*1024
  bf16_t* ow_b = Wqkv_b + 1572864;       // 1024*1024
  bf16_t* gw_b = ow_b + 1048576;
  bf16_t* pwr_b = gw_b + 1048576;
  bf16_t* pwi_b = pwr_b + 1048576;
  bf16_t* XLr = pwi_b + 1048576;         // 1024*1024
  bf16_t* XLi = XLr + 1048576;
  bf16_t* gmean = XLi + 1048576;         // 256*1024
  bf16_t* QKVbr = gmean + 262144;        // 1024*1536
  bf16_t* QKVbi = QKVbr + 1572864;
  bf16_t* Obr = QKVbi + 1572864;         // 1024*1024
  bf16_t* Obi = Obr + 1048576;
  bf16_t* Gr = Obi + 1048576;            // 7424*1024
  bf16_t* Gi = Gr + 7602176;             // total ~136 MB

  // 1) rfft of each chunk -> Xh fp32 + bf16 X_low pack + bf16 chunk-mean
  dft_kernel<<<dim3(4, 256), 256, 0, stream>>>(hidden, Xh, XLr, XLi, gmean);
  // 2) weights -> bf16
  concat_w<<<1536, 256, 0, stream>>>(q_w, k_w, v_w, Wqkv_b);
  cvt_bf16<<<1024, 256, 0, stream>>>(o_w, ow_b, 262144);
  cvt_bf16<<<1024, 256, 0, stream>>>(gate_w, gw_b, 262144);
  cvt_bf16<<<1024, 256, 0, stream>>>(pw_r, pwr_b, 262144);
  cvt_bf16<<<1024, 256, 0, stream>>>(pw_i, pwi_b, 262144);
  // 3) QKV projections (real & imag via z), bf16 out
  mmbf_kernel<EP_NONE><<<dim3(8, 12, 2), 256, 0, stream>>>(
      XLr, XLi, Wqkv_b, Wqkv_b, 1536, 1024, QKVbr, QKVbi, nullptr, nullptr,
      nullptr, nullptr);
  // 4) gate = sigmoid(mean @ gate_w^T)  (gmean already /64)
  mmbf_kernel<EP_SIGMOID><<<dim3(2, 8, 1), 256, 0, stream>>>(
      gmean, gmean, gw_b, gw_b, 1024, 1024, gg, gg, nullptr, nullptr,
      nullptr, nullptr);
  // 5) MFMA flash attention (real & imag), bf16 O out
  attn_mfma<<<dim3(16, 16, 2), 256, 0, stream>>>(QKVbr, QKVbi, Obr, Obi);
  // 6) O projection + alpha*A_low + (1-alpha)*X_low
  mmbf_kernel<EP_FUSELOW><<<dim3(8, 8, 2), 256, 0, stream>>>(
      Obr, Obi, ow_b, ow_b, 1024, 1024, Afr, Afi, Xh, nullptr, nullptr,
      alpha_raw);
  // 7) depthwise causal conv + exact GELU on high bins, bf16 out
  dwconv_kernel<<<dim3(4, 256, 2), 256, 0, stream>>>(Xh, dw_r, dw_i, Gr, Gi);
  // 8) pointwise conv + gate + residual, in-place into Xh high rows
  mmbf_kernel<EP_HIGH><<<dim3(58, 8, 2), 256, 0, stream>>>(
      Gr, Gi, pwr_b, pwi_b, 1024, 1024, nullptr, nullptr, Xh, Xh, gg,
      alpha_raw);
  // 9) irfft -> output
  irfft_kernel<<<dim3(4, 256), 256, 0, stream>>>(Xh, Afr, Afi, out);
}

// Round 4
// 405.410 us; speedup vs baseline: 2.7894x; 1.0193x over previous
//
#include <hip/hip_runtime.h>
#include <math.h>

// ---------------------------------------------------------------------------
// CausalHFPLayer: B=4, N=4096, D=1024, C=64 -> nc=64 chunks/batch, BC=256
// rfft bins M=33, k_low=4, high bins 29. NH=16, NKV=4, HD=64, T=256.
// Round 4: GEMMs use global_load_lds (m97 structure); Xh spectral buffer bf16.
// ---------------------------------------------------------------------------

typedef __bf16 bf16_t;
typedef bf16_t bf16x8 __attribute__((ext_vector_type(8)));
typedef float f32x4 __attribute__((ext_vector_type(4)));

#define EP_NONE 0
#define EP_SIGMOID 1
#define EP_FUSELOW 2
#define EP_HIGH 3

// async global->LDS 16B copy. LDS dest is wave-uniform base + lane*16, so the
// lds pointer must be identical across the wave's lanes (m104/m108).
__device__ __forceinline__ void gld_lds16(const bf16_t* g, bf16_t* l) {
  __builtin_amdgcn_global_load_lds(
      (const __attribute__((address_space(1))) unsigned int*)g,
      (__attribute__((address_space(3))) unsigned int*)l, 16, 0, 0);
}

// ============================ DFT (rfft) kernel ============================
// thread = (bc, d). 64 time samples -> 33 complex bins. Xh is bf16:
// Xh[bc][f][d] real rows 0..32, imag rows 33..65. Also emits contiguous bf16
// X_low pack [b*256+t][1024] and bf16 chunk-mean (bin0/64).
__global__ __launch_bounds__(256) void dft_kernel(const float* __restrict__ X,
                                                  bf16_t* __restrict__ Xh,
                                                  bf16_t* __restrict__ XLr,
                                                  bf16_t* __restrict__ XLi,
                                                  bf16_t* __restrict__ gmean) {
  const int d = blockIdx.x * 256 + threadIdx.x;
  const long bc = blockIdx.y;
  const int b = (int)(bc >> 6), ch = (int)(bc & 63);
  const float* xp = X + (bc * 64) * 1024 + d;
  float x[64];
#pragma unroll
  for (int t = 0; t < 64; t++) x[t] = xp[(long)t * 1024];
#pragma unroll
  for (int t = 0; t < 32; t++) {
    float a = x[t], bb = x[t + 32];
    x[t] = a + bb;
    x[t + 32] = a - bb;
  }
  bf16_t* outp = Xh + bc * 66 * 1024 + d;
  const float W = -6.283185307179586f / 64.f;
  for (int f = 0; f <= 32; f += 2) {
    float sd, cd;
    __sincosf(W * f, &sd, &cd);
    float c = 1.f, s = 0.f, ar = 0.f, ai = 0.f;
#pragma unroll
    for (int t = 0; t < 32; t++) {
      ar = fmaf(x[t], c, ar);
      ai = fmaf(x[t], s, ai);
      float cn = c * cd - s * sd;
      s = s * cd + c * sd;
      c = cn;
    }
    outp[(long)f * 1024] = (bf16_t)ar;
    outp[(long)(33 + f) * 1024] = (bf16_t)ai;
    if (f < 4) {
      long xr = ((long)(b * 256 + ch * 4 + f)) * 1024 + d;
      XLr[xr] = (bf16_t)ar;
      XLi[xr] = (bf16_t)ai;
    }
    if (f == 0) gmean[bc * 1024 + d] = (bf16_t)(ar * (1.f / 64.f));
  }
  for (int f = 1; f <= 31; f += 2) {
    float sd, cd;
    __sincosf(W * f, &sd, &cd);
    float c = 1.f, s = 0.f, ar = 0.f, ai = 0.f;
#pragma unroll
    for (int t = 0; t < 32; t++) {
      ar = fmaf(x[32 + t], c, ar);
      ai = fmaf(x[32 + t], s, ai);
      float cn = c * cd - s * sd;
      s = s * cd + c * sd;
      c = cn;
    }
    outp[(long)f * 1024] = (bf16_t)ar;
    outp[(long)(33 + f) * 1024] = (bf16_t)ai;
    if (f < 4) {
      long xr = ((long)(b * 256 + ch * 4 + f)) * 1024 + d;
      XLr[xr] = (bf16_t)ar;
      XLi[xr] = (bf16_t)ai;
    }
  }
}

// ==================== weight concat / convert to bf16 ======================
__global__ __launch_bounds__(256) void concat_w(const float* __restrict__ qw,
                                                const float* __restrict__ kw,
                                                const float* __restrict__ vw,
                                                bf16_t* __restrict__ W) {
  int i = blockIdx.x * 256 + threadIdx.x;  // float4 index, total 393216
  float4 v;
  if (i < 262144) v = ((const float4*)qw)[i];
  else if (i < 327680) v = ((const float4*)kw)[i - 262144];
  else v = ((const float4*)vw)[i - 327680];
  bf16_t* o = W + (long)i * 4;
  o[0] = (bf16_t)v.x; o[1] = (bf16_t)v.y; o[2] = (bf16_t)v.z; o[3] = (bf16_t)v.w;
}

// one kernel converts 4 weight matrices (z selects), 262144 float4 each
__global__ __launch_bounds__(256) void cvt4_bf16(const float* __restrict__ s0,
                                                 const float* __restrict__ s1,
                                                 const float* __restrict__ s2,
                                                 const float* __restrict__ s3,
                                                 bf16_t* __restrict__ d0,
                                                 bf16_t* __restrict__ d1,
                                                 bf16_t* __restrict__ d2,
                                                 bf16_t* __restrict__ d3) {
  int i = blockIdx.x * 256 + threadIdx.x;
  const float* s = blockIdx.y == 0 ? s0 : blockIdx.y == 1 ? s1 : blockIdx.y == 2 ? s2 : s3;
  bf16_t* dst = blockIdx.y == 0 ? d0 : blockIdx.y == 1 ? d1 : blockIdx.y == 2 ? d2 : d3;
  float4 v = ((const float4*)s)[i];
  bf16_t* o = dst + (long)i * 4;
  o[0] = (bf16_t)v.x; o[1] = (bf16_t)v.y; o[2] = (bf16_t)v.z; o[3] = (bf16_t)v.w;
}

// ============================ bf16 MFMA GEMM ===============================
// C[M,N] = A[M,K] @ B[N,K]^T. 128x128 tile, BK=32, 2x2 waves x 4x4 mfma,
// global_load_lds(16B) staging into unpadded [row][k] LDS (m97 structure).
template <int EMODE>
__global__ __launch_bounds__(256) void mmbf_kernel(
    const bf16_t* __restrict__ A0, const bf16_t* __restrict__ A1,
    const bf16_t* __restrict__ B0, const bf16_t* __restrict__ B1,
    int N, int K,
    void* __restrict__ C0v, void* __restrict__ C1v,
    const bf16_t* __restrict__ E0, const bf16_t* __restrict__ E1,
    bf16_t* __restrict__ XhMut,
    const float* __restrict__ gate, const float* __restrict__ alpha_ptr) {
  constexpr int BM = 128, BN = 128, BK = 32;  // no pad: lane-order layout
  __shared__ bf16_t As[BM * BK];
  __shared__ bf16_t Bs[BN * BK];
  const int z = blockIdx.z;
  const bf16_t* A = z ? A1 : A0;
  const bf16_t* B = z ? B1 : B0;
  void* Cv = z ? C1v : C0v;
  const bf16_t* E = z ? E1 : E0;
  const int imoff = z ? 33 * 1024 : 0;
  const int tid = threadIdx.x;
  const int lane = tid & 63;
  const int wave = tid >> 6;
  const int wm = (wave & 1) * 64, wn = (wave >> 1) * 64;
  const int m0 = blockIdx.x * BM, n0 = blockIdx.y * BN;
  const int q = lane >> 4, mr = lane & 15;
  // staging: lane -> (row within 16-row wave group, 8-elem k group)
  const int lrow = lane >> 2, lk8 = (lane & 3) * 8;

  f32x4 acc[4][4];
#pragma unroll
  for (int i = 0; i < 4; i++)
#pragma unroll
    for (int j = 0; j < 4; j++) acc[i][j] = (f32x4){0.f, 0.f, 0.f, 0.f};

  const long arow0 = (long)(m0 + wave * 16 + lrow) * K + lk8;
  const long brow0 = (long)(n0 + wave * 16 + lrow) * K + lk8;

  for (int kb = 0; kb < K; kb += BK) {
#pragma unroll
    for (int it = 0; it < 2; it++) {
      // wave w stages rows [w*16 + it*64, +16); LDS base wave-uniform
      gld_lds16(A + arow0 + (long)it * 64 * K + kb, As + (wave * 16 + it * 64) * BK);
      gld_lds16(B + brow0 + (long)it * 64 * K + kb, Bs + (wave * 16 + it * 64) * BK);
    }
    __syncthreads();  // drains vmcnt(0) -> LDS tiles complete
    bf16x8 af[4], bfr[4];
#pragma unroll
    for (int mi = 0; mi < 4; mi++)
      af[mi] = *(const bf16x8*)&As[(wm + mi * 16 + mr) * BK + q * 8];
#pragma unroll
    for (int ni = 0; ni < 4; ni++)
      bfr[ni] = *(const bf16x8*)&Bs[(wn + ni * 16 + mr) * BK + q * 8];
#pragma unroll
    for (int mi = 0; mi < 4; mi++)
#pragma unroll
      for (int ni = 0; ni < 4; ni++)
        acc[mi][ni] = __builtin_amdgcn_mfma_f32_16x16x32_bf16(
            af[mi], bfr[ni], acc[mi][ni], 0, 0, 0);
    __syncthreads();  // LDS reads done before next stage overwrites
  }

  float alpha = 0.f;
  if constexpr (EMODE == EP_FUSELOW) alpha = 1.f / (1.f + __expf(-alpha_ptr[0]));
#pragma unroll
  for (int mi = 0; mi < 4; mi++) {
#pragma unroll
    for (int ni = 0; ni < 4; ni++) {
      int col = n0 + wn + ni * 16 + mr;
      int rbase = m0 + wm + mi * 16 + q * 4;
#pragma unroll
      for (int r = 0; r < 4; r++) {
        int row = rbase + r;
        float val = acc[mi][ni][r];
        if constexpr (EMODE == EP_NONE) {
          ((bf16_t*)Cv)[(long)row * N + col] = (bf16_t)val;
        } else if constexpr (EMODE == EP_SIGMOID) {
          ((float*)Cv)[(long)row * N + col] = 1.f / (1.f + __expf(-val));
        } else if constexpr (EMODE == EP_FUSELOW) {
          // E = contiguous bf16 X_low pack, same row/col indexing as C
          float xl = (float)E[(long)row * 1024 + col];
          ((float*)Cv)[(long)row * 1024 + col] = alpha * val + (1.f - alpha) * xl;
        } else {  // EP_HIGH: in-place A_high = val*g + X_high (Xh bf16)
          int bc = row / 29, l = row - bc * 29;
          long x = ((long)bc * 66 + 4 + l) * 1024 + imoff + col;
          XhMut[x] = (bf16_t)fmaf(val, gate[(long)bc * 1024 + col], (float)XhMut[x]);
        }
      }
    }
  }
}

// ====================== MFMA flash attention ===============================
// grid (NH=16, B*4 qtiles=16, 2). block 256 = 4 waves; wave w owns q rows
// [qt*64 + w*16, +16). Block-causal (chunk=4): kt<qt visible, kt==qt masked.
__global__ __launch_bounds__(256) void attn_mfma(const bf16_t* __restrict__ QKVr,
                                                 const bf16_t* __restrict__ QKVi,
                                                 bf16_t* __restrict__ Or_,
                                                 bf16_t* __restrict__ Oi_) {
  const int h = blockIdx.x;
  const int b = blockIdx.y >> 2, qt = blockIdx.y & 3;
  const bf16_t* QKV = blockIdx.z ? QKVi : QKVr;
  bf16_t* O = blockIdx.z ? Oi_ : Or_;
  const int kvh = h >> 2;
  const int tid = threadIdx.x;
  const int lane = tid & 63, wave = tid >> 6;
  const int mr = lane & 15, q4 = lane >> 4;

  __shared__ bf16_t Ks[64 * 72];
  __shared__ bf16_t Vt[64 * 72];
  __shared__ bf16_t Ps[4][16 * 72];

  bf16x8 af[2];
  {
    const bf16_t* qp =
        QKV + (long)(b * 256 + qt * 64 + wave * 16 + mr) * 1536 + h * 64;
    af[0] = *(const bf16x8*)(qp + q4 * 8);
    af[1] = *(const bf16x8*)(qp + 32 + q4 * 8);
  }
  f32x4 Oacc[4];
#pragma unroll
  for (int ni = 0; ni < 4; ni++) Oacc[ni] = (f32x4){0.f, 0.f, 0.f, 0.f};
  float mrow[4], lrow[4];
#pragma unroll
  for (int r = 0; r < 4; r++) { mrow[r] = -1e30f; lrow[r] = 0.f; }

  for (int kt = 0; kt <= qt; kt++) {
#pragma unroll
    for (int it = 0; it < 2; it++) {
      int idx = tid + it * 256;
      int key = idx >> 3, dg = idx & 7;
      const bf16_t* kp = QKV + (long)(b * 256 + kt * 64 + key) * 1536 + 1024 +
                         kvh * 64 + dg * 8;
      *(bf16x8*)&Ks[key * 72 + dg * 8] = *(const bf16x8*)kp;
      bf16x8 vv = *(const bf16x8*)(kp + 256);
#pragma unroll
      for (int j = 0; j < 8; j++) Vt[(dg * 8 + j) * 72 + key] = vv[j];
    }
    __syncthreads();

    f32x4 S[4];
#pragma unroll
    for (int ni = 0; ni < 4; ni++) {
      S[ni] = (f32x4){0.f, 0.f, 0.f, 0.f};
#pragma unroll
      for (int s = 0; s < 2; s++) {
        bf16x8 kb = *(const bf16x8*)&Ks[(ni * 16 + mr) * 72 + s * 32 + q4 * 8];
        S[ni] = __builtin_amdgcn_mfma_f32_16x16x32_bf16(af[s], kb, S[ni], 0, 0, 0);
      }
    }
#pragma unroll
    for (int ni = 0; ni < 4; ni++) {
#pragma unroll
      for (int r = 0; r < 4; r++) {
        float v = S[ni][r] * 0.125f;
        if (kt == qt) {
          int qrow = wave * 16 + q4 * 4 + r;
          int kcol = ni * 16 + mr;
          if ((qrow >> 2) < (kcol >> 2)) v = -1e30f;
        }
        S[ni][r] = v;
      }
    }
#pragma unroll
    for (int r = 0; r < 4; r++) {
      float mx = fmaxf(fmaxf(S[0][r], S[1][r]), fmaxf(S[2][r], S[3][r]));
#pragma unroll
      for (int off = 1; off < 16; off <<= 1) mx = fmaxf(mx, __shfl_xor(mx, off));
      float mn = fmaxf(mrow[r], mx);
      float sc = __expf(mrow[r] - mn);
      mrow[r] = mn;
      float rs = 0.f;
#pragma unroll
      for (int ni = 0; ni < 4; ni++) {
        float p = __expf(S[ni][r] - mn);
        rs += p;
        Ps[wave][(q4 * 4 + r) * 72 + ni * 16 + mr] = (bf16_t)p;
      }
#pragma unroll
      for (int off = 1; off < 16; off <<= 1) rs += __shfl_xor(rs, off);
      lrow[r] = lrow[r] * sc + rs;
#pragma unroll
      for (int ni = 0; ni < 4; ni++) Oacc[ni][r] *= sc;
    }
    bf16x8 pa[2];
    pa[0] = *(const bf16x8*)&Ps[wave][mr * 72 + q4 * 8];
    pa[1] = *(const bf16x8*)&Ps[wave][mr * 72 + 32 + q4 * 8];
#pragma unroll
    for (int ni = 0; ni < 4; ni++) {
#pragma unroll
      for (int s = 0; s < 2; s++) {
        bf16x8 vb = *(const bf16x8*)&Vt[(ni * 16 + mr) * 72 + s * 32 + q4 * 8];
        Oacc[ni] = __builtin_amdgcn_mfma_f32_16x16x32_bf16(pa[s], vb, Oacc[ni], 0, 0, 0);
      }
    }
    __syncthreads();
  }

#pragma unroll
  for (int r = 0; r < 4; r++) {
    float inv = 1.f / lrow[r];
    long row = b * 256 + qt * 64 + wave * 16 + q4 * 4 + r;
#pragma unroll
    for (int ni = 0; ni < 4; ni++)
      O[row * 1024 + h * 64 + ni * 16 + mr] = (bf16_t)(Oacc[ni][r] * inv);
  }
}

// ===================== depthwise causal conv + GELU ========================
__global__ __launch_bounds__(256) void dwconv_kernel(const bf16_t* __restrict__ Xh,
                                                     const float* __restrict__ dwr,
                                                     const float* __restrict__ dwi,
                                                     bf16_t* __restrict__ Gr,
                                                     bf16_t* __restrict__ Gi) {
  const int d = blockIdx.x * 256 + threadIdx.x;
  const int bc = blockIdx.y;
  const float* dw = blockIdx.z ? dwi : dwr;
  bf16_t* G = blockIdx.z ? Gi : Gr;
  const int imoff = blockIdx.z ? 33 * 1024 : 0;
  float w[7];
#pragma unroll
  for (int j = 0; j < 7; j++) w[j] = dw[d * 7 + j];
  float x[29];
#pragma unroll
  for (int l = 0; l < 29; l++)
    x[l] = (float)Xh[((long)bc * 66 + 4 + l) * 1024 + imoff + d];
#pragma unroll
  for (int l = 0; l < 29; l++) {
    float y = 0.f;
#pragma unroll
    for (int j = 0; j < 7; j++) {
      int src = l - 6 + j;
      if (src >= 0) y = fmaf(w[j], x[src], y);
    }
    float ge = 0.5f * y * (1.f + erff(y * 0.7071067811865475f));
    G[((long)bc * 29 + l) * 1024 + d] = (bf16_t)ge;
  }
}

// ============================ irfft + output ===============================
// Bins 0..3 from Af fp32 (alpha-fused low), 4..32 from bf16 Xh (= A_high
// in-place). Imag of bins 0/32 ignored (pocketfft c2r).
__global__ __launch_bounds__(256) void irfft_kernel(const bf16_t* __restrict__ Xh,
                                                    const float* __restrict__ Afr,
                                                    const float* __restrict__ Afi,
                                                    float* __restrict__ out) {
  const int d = blockIdx.x * 256 + threadIdx.x;
  const int bc = blockIdx.y;
  const int b = bc >> 6, t0 = (bc & 63) << 2;
  const long afbase = ((long)(b * 256 + t0)) * 1024 + d;
  const long xbase = (long)bc * 66 * 1024 + d;
  const float W = 6.283185307179586f / 64.f;
  float E[32], Od[32];
#pragma unroll
  for (int t = 0; t < 32; t++) { E[t] = 0.f; Od[t] = 0.f; }
  const float R0 = Afr[afbase];
  const float R32 = (float)Xh[xbase + 32 * 1024];
  for (int f = 2; f <= 30; f += 2) {
    float Rf = (f < 4) ? Afr[afbase + (long)f * 1024] : (float)Xh[xbase + (long)f * 1024];
    float If = (f < 4) ? Afi[afbase + (long)f * 1024]
                       : (float)Xh[xbase + (long)(33 + f) * 1024];
    float a = 2.f * Rf, bb = -2.f * If;
    float sd, cd;
    __sincosf(W * f, &sd, &cd);
    float c = 1.f, s = 0.f;
#pragma unroll
    for (int t = 0; t < 32; t++) {
      E[t] = fmaf(a, c, fmaf(bb, s, E[t]));
      float cn = c * cd - s * sd;
      s = s * cd + c * sd;
      c = cn;
    }
  }
  for (int f = 1; f <= 31; f += 2) {
    float Rf = (f < 4) ? Afr[afbase + (long)f * 1024] : (float)Xh[xbase + (long)f * 1024];
    float If = (f < 4) ? Afi[afbase + (long)f * 1024]
                       : (float)Xh[xbase + (long)(33 + f) * 1024];
    float a = 2.f * Rf, bb = -2.f * If;
    float sd, cd;
    __sincosf(W * f, &sd, &cd);
    float c = 1.f, s = 0.f;
#pragma unroll
    for (int t = 0; t < 32; t++) {
      Od[t] = fmaf(a, c, fmaf(bb, s, Od[t]));
      float cn = c * cd - s * sd;
      s = s * cd + c * sd;
      c = cn;
    }
  }
#pragma unroll
  for (int t = 0; t < 32; t++) {
    float base = R0 + ((t & 1) ? -R32 : R32);
    out[((long)(bc * 64 + t)) * 1024 + d] = (base + E[t] + Od[t]) * (1.f / 64.f);
    out[((long)(bc * 64 + t + 32)) * 1024 + d] = (base + E[t] - Od[t]) * (1.f / 64.f);
  }
}

// ============================ launcher =====================================
extern "C" void kernel_launch(void* const* d_in, const int* in_sizes, int n_in,
                              void* d_out, int out_size, void* d_ws, size_t ws_size,
                              hipStream_t stream) {
  const float* hidden = (const float*)d_in[0];
  const float* q_w = (const float*)d_in[1];
  const float* k_w = (const float*)d_in[2];
  const float* v_w = (const float*)d_in[3];
  const float* o_w = (const float*)d_in[4];
  const float* dw_r = (const float*)d_in[5];
  const float* pw_r = (const float*)d_in[6];
  const float* dw_i = (const float*)d_in[7];
  const float* pw_i = (const float*)d_in[8];
  const float* gate_w = (const float*)d_in[9];
  const float* alpha_raw = (const float*)d_in[10];
  float* out = (float*)d_out;

  float* ws = (float*)d_ws;
  // fp32 region
  float* Afr = ws;                       // 1024*1024
  float* Afi = Afr + 1048576;
  float* gg = Afi + 1048576;             // 256*1024
  // bf16 region
  bf16_t* bws = (bf16_t*)(gg + 262144);
  bf16_t* Xh = bws;                      // 256*66*1024 = 17,301,504 bf16
  bf16_t* Wqkv_b = Xh + 17301504;        // 1536*1024
  bf16_t* ow_b = Wqkv_b + 1572864;       // 1024*1024
  bf16_t* gw_b = ow_b + 1048576;
  bf16_t* pwr_b = gw_b + 1048576;
  bf16_t* pwi_b = pwr_b + 1048576;
  bf16_t* XLr = pwi_b + 1048576;         // 1024*1024
  bf16_t* XLi = XLr + 1048576;
  bf16_t* gmean = XLi + 1048576;         // 256*1024
  bf16_t* QKVbr = gmean + 262144;        // 1024*1536
  bf16_t* QKVbi = QKVbr + 1572864;
  bf16_t* Obr = QKVbi + 1572864;         // 1024*1024
  bf16_t* Obi = Obr + 1048576;
  bf16_t* Gr = Obi + 1048576;            // 7424*1024
  bf16_t* Gi = Gr + 7602176;             // total ~103 MB

  // 1) rfft -> bf16 Xh + bf16 X_low pack + bf16 chunk-mean
  dft_kernel<<<dim3(4, 256), 256, 0, stream>>>(hidden, Xh, XLr, XLi, gmean);
  // 2) weights -> bf16
  concat_w<<<1536, 256, 0, stream>>>(q_w, k_w, v_w, Wqkv_b);
  cvt4_bf16<<<dim3(1024, 4), 256, 0, stream>>>(o_w, gate_w, pw_r, pw_i,
                                               ow_b, gw_b, pwr_b, pwi_b);
  // 3) QKV projections (real & imag via z), bf16 out
  mmbf_kernel<EP_NONE><<<dim3(8, 12, 2), 256, 0, stream>>>(
      XLr, XLi, Wqkv_b, Wqkv_b, 1536, 1024, QKVbr, QKVbi, nullptr, nullptr,
      nullptr, nullptr, nullptr);
  // 4) gate = sigmoid(mean @ gate_w^T)  (gmean already /64)
  mmbf_kernel<EP_SIGMOID><<<dim3(2, 8, 1), 256, 0, stream>>>(
      gmean, gmean, gw_b, gw_b, 1024, 1024, gg, gg, nullptr, nullptr,
      nullptr, nullptr, nullptr);
  // 5) MFMA flash attention (real & imag), bf16 O out
  attn_mfma<<<dim3(16, 16, 2), 256, 0, stream>>>(QKVbr, QKVbi, Obr, Obi);
  // 6) O projection + alpha*A_low + (1-alpha)*X_low -> fp32 Af
  mmbf_kernel<EP_FUSELOW><<<dim3(8, 8, 2), 256, 0, stream>>>(
      Obr, Obi, ow_b, ow_b, 1024, 1024, Afr, Afi, XLr, XLi,
      nullptr, nullptr, alpha_raw);
  // 7) depthwise causal conv + exact GELU on high bins, bf16 out
  dwconv_kernel<<<dim3(4, 256, 2), 256, 0, stream>>>(Xh, dw_r, dw_i, Gr, Gi);
  // 8) pointwise conv + gate + residual, in-place into bf16 Xh high rows
  mmbf_kernel<EP_HIGH><<<dim3(58, 8, 2), 256, 0, stream>>>(
      Gr, Gi, pwr_b, pwi_b, 1024, 1024, nullptr, nullptr, nullptr, nullptr,
      Xh, gg, alpha_raw);
  // 9) irfft -> output
  irfft_kernel<<<dim3(4, 256), 256, 0, stream>>>(Xh, Afr, Afi, out);
}